// Round 20
// baseline (699.699 us; speedup 1.0000x reference)
//
#include <hip/hip_runtime.h>
#include <hip/hip_bf16.h>

// MiniMax MoE top-2, MI355X. T=2048, H=2048, F=4096, E=8.
// Round 20: R18 base (best 556us). gemm1 restructured as two sequential
// phases (g then u) inside one block sharing the A-tile: BN=128, acc=64
// AGPR per phase, g stashed bf16 in hbuf, phase 2 applies silu(g)*u.
// Logical traffic 2.1 -> 1.6 GB. gemm2 / router / combine R18-exact.

#define T_TOK 2048
#define H_DIM 2048
#define F_DIM 4096
#define E_NUM 8
#define NPAIR (T_TOK * 2)

typedef __attribute__((ext_vector_type(8))) short short8;
typedef __attribute__((ext_vector_type(4))) float f32x4;

__device__ __forceinline__ unsigned short f2bf(float f) {
    unsigned u = __builtin_bit_cast(unsigned, f);
    u = (u + 0x7FFFu + ((u >> 16) & 1u)) >> 16;   // RNE
    return (unsigned short)u;
}

__device__ __forceinline__ float bf2f(unsigned short us) {
    unsigned u = ((unsigned)us) << 16;
    return __builtin_bit_cast(float, u);
}

__device__ __forceinline__ uint4 pack8(float4 a, float4 b) {
    uint4 o;
    o.x = f2bf(a.x) | ((unsigned)f2bf(a.y) << 16);
    o.y = f2bf(a.z) | ((unsigned)f2bf(a.w) << 16);
    o.z = f2bf(b.x) | ((unsigned)f2bf(b.y) << 16);
    o.w = f2bf(b.z) | ((unsigned)f2bf(b.w) << 16);
    return o;
}

__device__ __forceinline__ uint2 pack4(float4 a) {
    uint2 o;
    o.x = f2bf(a.x) | ((unsigned)f2bf(a.y) << 16);
    o.y = f2bf(a.z) | ((unsigned)f2bf(a.w) << 16);
    return o;
}

__device__ __forceinline__ void gload16(const void* g, void* s) {
    __builtin_amdgcn_global_load_lds(
        (const __attribute__((address_space(1))) unsigned int*)g,
        (__attribute__((address_space(3))) unsigned int*)s, 16, 0, 0);
}

// ---- router + x->bf16 conversion (fused, R18-exact) --------------------
__global__ void k_router(const float* __restrict__ x, const float* __restrict__ gw,
                         ushort* __restrict__ xb,
                         int2* __restrict__ eidx, float2* __restrict__ ew,
                         int* __restrict__ cnt) {
    int t = blockIdx.x * 4 + (threadIdx.x >> 6);
    int lane = threadIdx.x & 63;
    const float* xr = x + (size_t)t * H_DIM;
    ushort* xbr = xb + (size_t)t * H_DIM;

    #pragma unroll
    for (int j = 0; j < 4; j++) {
        int idx = (j * 64 + lane) * 8;
        const float4* p = (const float4*)(xr + idx);
        uint2 lo = pack4(p[0]), hi = pack4(p[1]);
        *(uint4*)(xbr + idx) = make_uint4(lo.x, lo.y, hi.x, hi.y);
    }

    float l[E_NUM];
    #pragma unroll
    for (int e = 0; e < E_NUM; e++) {
        const float* wr = gw + (size_t)e * H_DIM;
        float acc = 0.f;
        for (int i = lane; i < H_DIM; i += 64) acc += xr[i] * wr[i];
        #pragma unroll
        for (int o = 32; o; o >>= 1) acc += __shfl_xor(acc, o);
        l[e] = acc;
    }
    if (lane == 0) {
        int e0 = 0;
        #pragma unroll
        for (int e = 1; e < E_NUM; e++) if (l[e] > l[e0]) e0 = e;
        int e1 = -1;
        #pragma unroll
        for (int e = 0; e < E_NUM; e++) {
            if (e == e0) continue;
            if (e1 < 0 || l[e] > l[e1]) e1 = e;
        }
        float s1 = expf(l[e1] - l[e0]);
        float w0 = 1.f / (1.f + s1);
        float w1 = s1 * w0;
        eidx[t] = make_int2(e0, e1);
        ew[t]   = make_float2(w0, w1);
        atomicAdd(&cnt[e0], 1);
        atomicAdd(&cnt[e1], 1);
    }
}

// ---- offsets + expert-major scatter (fused, R18-exact) -----------------
__global__ void k_offfill(const int* __restrict__ cnt, int* __restrict__ off,
                          const int2* __restrict__ eidx,
                          int* __restrict__ ptok, int2* __restrict__ inv) {
    __shared__ int soff[E_NUM];
    __shared__ int scnt[E_NUM];
    if (threadIdx.x == 0) {
        int s = 0;
        for (int e = 0; e < E_NUM; e++) { soff[e] = s; off[e] = s; s += cnt[e]; scnt[e] = 0; }
        off[E_NUM] = s;
    }
    __syncthreads();
    for (int t = threadIdx.x; t < T_TOK; t += blockDim.x) {
        int2 e = eidx[t];
        int p0 = soff[e.x] + atomicAdd(&scnt[e.x], 1);
        ptok[p0] = t;
        int p1 = soff[e.y] + atomicAdd(&scnt[e.y], 1);
        ptok[p1] = t;
        inv[t] = make_int2(p0, p1);
    }
}

// ---- grouped GEMM1: two-phase (g then u), shared A-tile ----------------
// BM=256 x BN=128 x BK=64, 512 thr = 8 waves (4m x 2n), wave tile 64x64.
// Phase 0: hbuf = bf16(X Wg^T). Phase 1: u = X Wu^T; h = silu(g)*u in place.
// A: global_load_lds (re-staged per phase); B: reg-staged fp32->bf16.
__global__ __launch_bounds__(512, 4) void k_gemm1(
        const ushort* __restrict__ xb, const float* __restrict__ wg,
        const float* __restrict__ wu, const int* __restrict__ ptok,
        const int* __restrict__ off, ushort* __restrict__ hbuf) {
    __shared__ __align__(16) ushort As[256 * 64];   // 32 KB
    __shared__ __align__(16) ushort Bs[128 * 64];   // 16 KB

    int e = blockIdx.y >> 3, mt = blockIdx.y & 7;
    int base = off[e], ne = off[e + 1] - base;
    int row0 = mt * 256;
    if (row0 >= ne) return;
    int nb = blockIdx.x * 128;   // F-columns

    int tid = threadIdx.x;
    int wv = tid >> 6, l = tid & 63;
    int lr = l & 15, lk = l >> 4;
    int wm = wv >> 1, wn = wv & 1;

    int wvu = __builtin_amdgcn_readfirstlane(wv);
    const ushort* srcA[4];
    int sslot = 8 * ((l & 7) ^ ((l >> 3) & 7));
    #pragma unroll
    for (int c = 0; c < 4; c++) {
        int r = (wvu * 4 + c) * 8 + (l >> 3);
        int pp = base + min(row0 + r, ne - 1);
        srcA[c] = xb + (size_t)ptok[pp] * H_DIM + sslot;
    }

    // B staging: 4 thr/row (128 rows), 16 floats -> two 16B slots (proven map)
    int brow = tid >> 2, bs = tid & 3;
    size_t woff = ((size_t)e * F_DIM + nb + brow) * H_DIM + bs * 16;
    int bsw = (brow & 7) << 4;
    int bo0 = brow * 64 + (((bs * 32) ^ bsw) >> 1);
    int bo1 = brow * 64 + (((bs * 32 + 16) ^ bsw) >> 1);

    int rsw = (lr & 7) << 4;

    #pragma unroll 1
    for (int ph = 0; ph < 2; ph++) {
        const float* wrow = (ph ? wu : wg) + woff;
        f32x4 acc[4][4] = {};

        for (int kb = 0; kb < H_DIM; kb += 64) {
            __syncthreads();
            #pragma unroll
            for (int c = 0; c < 4; c++)
                gload16(srcA[c] + kb, (ushort*)As + (wvu * 4 + c) * 512);
            float4 b0 = *(const float4*)(wrow + kb);
            float4 b1 = *(const float4*)(wrow + kb + 4);
            float4 b2 = *(const float4*)(wrow + kb + 8);
            float4 b3 = *(const float4*)(wrow + kb + 12);
            *(uint4*)(&Bs[bo0]) = pack8(b0, b1);
            *(uint4*)(&Bs[bo1]) = pack8(b2, b3);
            __syncthreads();

            #pragma unroll
            for (int kk = 0; kk < 2; kk++) {
                int kby = kk * 64 + lk * 16;
                short8 a[4];
                #pragma unroll
                for (int m = 0; m < 4; m++) {
                    int row = wm * 64 + m * 16 + lr;
                    a[m] = *(const short8*)(&As[(row * 128 + (kby ^ rsw)) >> 1]);
                }
                #pragma unroll
                for (int n = 0; n < 4; n++) {
                    int rowb = wn * 64 + n * 16 + lr;
                    short8 b8 = *(const short8*)(&Bs[(rowb * 128 + (kby ^ rsw)) >> 1]);
                    #pragma unroll
                    for (int m = 0; m < 4; m++)
                        acc[m][n] = __builtin_amdgcn_mfma_f32_16x16x32_bf16(a[m], b8, acc[m][n], 0, 0, 0);
                }
            }
        }

        // epilogue (C map: col=lane&15, row=(lane>>4)*4+r)
        #pragma unroll
        for (int m = 0; m < 4; m++) {
            #pragma unroll
            for (int r = 0; r < 4; r++) {
                int lrow = wm * 64 + m * 16 + lk * 4 + r;
                if (row0 + lrow < ne) {
                    ushort* hb = hbuf + (size_t)(base + row0 + lrow) * F_DIM + nb;
                    #pragma unroll
                    for (int n = 0; n < 4; n++) {
                        int col = wn * 64 + n * 16 + lr;
                        if (ph == 0) {
                            hb[col] = f2bf(acc[m][n][r]);     // stash g
                        } else {
                            float g = bf2f(hb[col]);          // phase-1 value
                            float u = acc[m][n][r];
                            hb[col] = f2bf(g / (1.f + __expf(-g)) * u);
                        }
                    }
                }
            }
        }
    }
}

// ---- grouped GEMM2: ybuf[p] = h[p] Wd^T  (R18-exact body) --------------
// BM=256 x BN=128 x BK=64, 512 thr = 8 waves (4m x 2n), wave tile 64x64.
__global__ __launch_bounds__(512, 2) void k_gemm2(
        const ushort* __restrict__ hbuf, const float* __restrict__ wd,
        const int* __restrict__ off, float* __restrict__ ybuf) {
    __shared__ __align__(16) ushort As[256 * 64];   // 32 KB
    __shared__ __align__(16) ushort Bs[128 * 64];   // 16 KB

    int e = blockIdx.y >> 3, mt = blockIdx.y & 7;
    int base = off[e], ne = off[e + 1] - base;
    int row0 = mt * 256;
    if (row0 >= ne) return;
    int nb = blockIdx.x * 128;

    int tid = threadIdx.x;
    int wv = tid >> 6, l = tid & 63;
    int lr = l & 15, lk = l >> 4;
    int wm = wv >> 1, wn = wv & 1;

    int wvu = __builtin_amdgcn_readfirstlane(wv);
    const ushort* srcA[4];
    int sslot = 8 * ((l & 7) ^ ((l >> 3) & 7));
    #pragma unroll
    for (int c = 0; c < 4; c++) {
        int r = (wvu * 4 + c) * 8 + (l >> 3);
        int pp = base + min(row0 + r, ne - 1);
        srcA[c] = hbuf + (size_t)pp * F_DIM + sslot;
    }

    int brow = tid >> 2, bs = tid & 3;
    const float* wdrow = wd + ((size_t)e * H_DIM + nb + brow) * F_DIM + bs * 16;
    int bsw = (brow & 7) << 4;
    int bo0 = brow * 64 + (((bs * 32) ^ bsw) >> 1);
    int bo1 = brow * 64 + (((bs * 32 + 16) ^ bsw) >> 1);

    int rsw = (lr & 7) << 4;

    f32x4 acc[4][4] = {};

    for (int kb = 0; kb < F_DIM; kb += 64) {
        __syncthreads();
        #pragma unroll
        for (int c = 0; c < 4; c++)
            gload16(srcA[c] + kb, (ushort*)As + (wvu * 4 + c) * 512);
        float4 b0 = *(const float4*)(wdrow + kb);
        float4 b1 = *(const float4*)(wdrow + kb + 4);
        float4 b2 = *(const float4*)(wdrow + kb + 8);
        float4 b3 = *(const float4*)(wdrow + kb + 12);
        *(uint4*)(&Bs[bo0]) = pack8(b0, b1);
        *(uint4*)(&Bs[bo1]) = pack8(b2, b3);
        __syncthreads();

        #pragma unroll
        for (int kk = 0; kk < 2; kk++) {
            int kby = kk * 64 + lk * 16;
            short8 a[4];
            #pragma unroll
            for (int m = 0; m < 4; m++) {
                int row = wm * 64 + m * 16 + lr;
                a[m] = *(const short8*)(&As[(row * 128 + (kby ^ rsw)) >> 1]);
            }
            #pragma unroll
            for (int n = 0; n < 4; n++) {
                int rowb = wn * 64 + n * 16 + lr;
                short8 b8 = *(const short8*)(&Bs[(rowb * 128 + (kby ^ rsw)) >> 1]);
                #pragma unroll
                for (int m = 0; m < 4; m++)
                    acc[m][n] = __builtin_amdgcn_mfma_f32_16x16x32_bf16(a[m], b8, acc[m][n], 0, 0, 0);
            }
        }
    }

    #pragma unroll
    for (int m = 0; m < 4; m++) {
        #pragma unroll
        for (int r = 0; r < 4; r++) {
            int lrow = wm * 64 + m * 16 + lk * 4 + r;
            if (row0 + lrow < ne) {
                float* yrow = ybuf + (size_t)(base + row0 + lrow) * H_DIM + nb;
                #pragma unroll
                for (int n = 0; n < 4; n++)
                    yrow[wn * 64 + n * 16 + lr] = acc[m][n][r];
            }
        }
    }
}

// ---- combine: out[t] = w0*y[p0] + w1*y[p1]  (R18-exact) ----------------
__global__ void k_combine(const float* __restrict__ ybuf,
                          const float2* __restrict__ ew,
                          const int2* __restrict__ inv,
                          float* __restrict__ out) {
    int t = blockIdx.x;
    float2 w = ew[t];
    int2 pp = inv[t];
    const float4* y0 = (const float4*)(ybuf + (size_t)pp.x * H_DIM);
    const float4* y1 = (const float4*)(ybuf + (size_t)pp.y * H_DIM);
    float4* o = (float4*)(out + (size_t)t * H_DIM);
    for (int j = threadIdx.x; j < H_DIM / 4; j += blockDim.x) {
        float4 a = y0[j], b = y1[j];
        float4 r;
        r.x = w.x * a.x + w.y * b.x;
        r.y = w.x * a.y + w.y * b.y;
        r.z = w.x * a.z + w.y * b.z;
        r.w = w.x * a.w + w.y * b.w;
        o[j] = r;
    }
}

extern "C" void kernel_launch(void* const* d_in, const int* in_sizes, int n_in,
                              void* d_out, int out_size, void* d_ws, size_t ws_size,
                              hipStream_t stream) {
    const float* x  = (const float*)d_in[0];
    const float* gw = (const float*)d_in[1];
    const float* wg = (const float*)d_in[2];
    const float* wu = (const float*)d_in[3];
    const float* wd = (const float*)d_in[4];
    float* out = (float*)d_out;

    char* ws = (char*)d_ws;
    size_t o = 0;
    ushort* xb   = (ushort*)(ws + o); o += (size_t)T_TOK * H_DIM * 2;   //  8 MB
    ushort* hbuf = (ushort*)(ws + o); o += (size_t)NPAIR * F_DIM * 2;   // 32 MB
    float*  ybuf = (float*) (ws + o); o += (size_t)NPAIR * H_DIM * 4;   // 32 MB
    int*    ptok = (int*)   (ws + o); o += NPAIR * 4;
    int2*   eidx = (int2*)  (ws + o); o += T_TOK * 8;
    float2* ew   = (float2*)(ws + o); o += T_TOK * 8;
    int2*   inv  = (int2*)  (ws + o); o += T_TOK * 8;
    int*    cnt  = (int*)   (ws + o); o += 256;
    int*    off  = (int*)   (ws + o); o += 256;

    hipMemsetAsync(cnt, 0, 256, stream);

    k_router <<<T_TOK / 4, 256, 0, stream>>>(x, gw, xb, eidx, ew, cnt);
    k_offfill<<<1, 256, 0, stream>>>(cnt, off, eidx, ptok, inv);

    dim3 g1(F_DIM / 128, E_NUM * 8);     // x: ntile(128) over F, y: e*8 + mtile(256)
    k_gemm1<<<g1, 512, 0, stream>>>(xb, wg, wu, ptok, off, hbuf);
    dim3 g2(H_DIM / 128, E_NUM * 8);     // x: ntile(128) over H, y: e*8 + mtile(256)
    k_gemm2<<<g2, 512, 0, stream>>>(hbuf, wd, off, ybuf);
    k_combine<<<T_TOK, 256, 0, stream>>>(ybuf, ew, inv, out);
}

// Round 21
// 554.717 us; speedup vs baseline: 1.2614x; 1.2614x over previous
//
#include <hip/hip_runtime.h>
#include <hip/hip_bf16.h>

// MiniMax MoE top-2, MI355X. T=2048, H=2048, F=4096, E=8.
// Round 21: REVERT to R18 byte-exact (session best: 555.9us).
// R13-R20 structural sweep (split-K x2, residency x2, bf16-weights, B-rotation,
// combine-fusion, two-phase gemm1) all neutral or regressed vs this config.

#define T_TOK 2048
#define H_DIM 2048
#define F_DIM 4096
#define E_NUM 8
#define NPAIR (T_TOK * 2)

typedef __attribute__((ext_vector_type(8))) short short8;
typedef __attribute__((ext_vector_type(4))) float f32x4;

__device__ __forceinline__ unsigned short f2bf(float f) {
    unsigned u = __builtin_bit_cast(unsigned, f);
    u = (u + 0x7FFFu + ((u >> 16) & 1u)) >> 16;   // RNE
    return (unsigned short)u;
}

__device__ __forceinline__ uint4 pack8(float4 a, float4 b) {
    uint4 o;
    o.x = f2bf(a.x) | ((unsigned)f2bf(a.y) << 16);
    o.y = f2bf(a.z) | ((unsigned)f2bf(a.w) << 16);
    o.z = f2bf(b.x) | ((unsigned)f2bf(b.y) << 16);
    o.w = f2bf(b.z) | ((unsigned)f2bf(b.w) << 16);
    return o;
}

__device__ __forceinline__ uint2 pack4(float4 a) {
    uint2 o;
    o.x = f2bf(a.x) | ((unsigned)f2bf(a.y) << 16);
    o.y = f2bf(a.z) | ((unsigned)f2bf(a.w) << 16);
    return o;
}

__device__ __forceinline__ void gload16(const void* g, void* s) {
    __builtin_amdgcn_global_load_lds(
        (const __attribute__((address_space(1))) unsigned int*)g,
        (__attribute__((address_space(3))) unsigned int*)s, 16, 0, 0);
}

// ---- router + x->bf16 conversion (fused) -------------------------------
__global__ void k_router(const float* __restrict__ x, const float* __restrict__ gw,
                         ushort* __restrict__ xb,
                         int2* __restrict__ eidx, float2* __restrict__ ew,
                         int* __restrict__ cnt) {
    int t = blockIdx.x * 4 + (threadIdx.x >> 6);
    int lane = threadIdx.x & 63;
    const float* xr = x + (size_t)t * H_DIM;
    ushort* xbr = xb + (size_t)t * H_DIM;

    #pragma unroll
    for (int j = 0; j < 4; j++) {
        int idx = (j * 64 + lane) * 8;
        const float4* p = (const float4*)(xr + idx);
        uint2 lo = pack4(p[0]), hi = pack4(p[1]);
        *(uint4*)(xbr + idx) = make_uint4(lo.x, lo.y, hi.x, hi.y);
    }

    float l[E_NUM];
    #pragma unroll
    for (int e = 0; e < E_NUM; e++) {
        const float* wr = gw + (size_t)e * H_DIM;
        float acc = 0.f;
        for (int i = lane; i < H_DIM; i += 64) acc += xr[i] * wr[i];
        #pragma unroll
        for (int o = 32; o; o >>= 1) acc += __shfl_xor(acc, o);
        l[e] = acc;
    }
    if (lane == 0) {
        int e0 = 0;
        #pragma unroll
        for (int e = 1; e < E_NUM; e++) if (l[e] > l[e0]) e0 = e;
        int e1 = -1;
        #pragma unroll
        for (int e = 0; e < E_NUM; e++) {
            if (e == e0) continue;
            if (e1 < 0 || l[e] > l[e1]) e1 = e;
        }
        float s1 = expf(l[e1] - l[e0]);
        float w0 = 1.f / (1.f + s1);
        float w1 = s1 * w0;
        eidx[t] = make_int2(e0, e1);
        ew[t]   = make_float2(w0, w1);
        atomicAdd(&cnt[e0], 1);
        atomicAdd(&cnt[e1], 1);
    }
}

// ---- offsets + expert-major scatter (fused, single block) --------------
__global__ void k_offfill(const int* __restrict__ cnt, int* __restrict__ off,
                          const int2* __restrict__ eidx,
                          int* __restrict__ ptok, int2* __restrict__ inv) {
    __shared__ int soff[E_NUM];
    __shared__ int scnt[E_NUM];
    if (threadIdx.x == 0) {
        int s = 0;
        for (int e = 0; e < E_NUM; e++) { soff[e] = s; off[e] = s; s += cnt[e]; scnt[e] = 0; }
        off[E_NUM] = s;
    }
    __syncthreads();
    for (int t = threadIdx.x; t < T_TOK; t += blockDim.x) {
        int2 e = eidx[t];
        int p0 = soff[e.x] + atomicAdd(&scnt[e.x], 1);
        ptok[p0] = t;
        int p1 = soff[e.y] + atomicAdd(&scnt[e.y], 1);
        ptok[p1] = t;
        inv[t] = make_int2(p0, p1);
    }
}

// ---- grouped GEMM1: h = silu(X Wg^T) * (X Wu^T)  (R12-exact body) ------
// BM=256 x BN=64 x BK=64, 512 thr = 8 waves (4m x 2n), wave tile 64x32.
// A: global_load_lds (wave-uniform base, pre-swizzled source).
__global__ __launch_bounds__(512, 4) void k_gemm1(
        const ushort* __restrict__ xb, const float* __restrict__ wg,
        const float* __restrict__ wu, const int* __restrict__ ptok,
        const int* __restrict__ off, ushort* __restrict__ hbuf) {
    __shared__ __align__(16) ushort As[256 * 64];   // 32 KB
    __shared__ __align__(16) ushort Bg[64 * 64];    //  8 KB
    __shared__ __align__(16) ushort Bu[64 * 64];    //  8 KB

    int e = blockIdx.y >> 3, mt = blockIdx.y & 7;   // ne <= 2048 -> mt < 8 exact
    int base = off[e], ne = off[e + 1] - base;
    int row0 = mt * 256;
    if (row0 >= ne) return;
    int nb = blockIdx.x * 64;

    int tid = threadIdx.x;
    int wv = tid >> 6, l = tid & 63;
    int lr = l & 15, lk = l >> 4;
    int wm = wv >> 1, wn = wv & 1;

    int wvu = __builtin_amdgcn_readfirstlane(wv);
    const ushort* srcA[4];
    int sslot = 8 * ((l & 7) ^ ((l >> 3) & 7));
    #pragma unroll
    for (int c = 0; c < 4; c++) {
        int r = (wvu * 4 + c) * 8 + (l >> 3);
        int pp = base + min(row0 + r, ne - 1);
        srcA[c] = xb + (size_t)ptok[pp] * H_DIM + sslot;
    }

    int brow = tid >> 3, bs = tid & 7;
    const float* wgrow = wg + ((size_t)e * F_DIM + nb + brow) * H_DIM + bs * 8;
    const float* wurow = wu + ((size_t)e * F_DIM + nb + brow) * H_DIM + bs * 8;
    int bo = brow * 64 + (((bs * 16) ^ ((brow & 7) << 4)) >> 1);

    int rsw = (lr & 7) << 4;

    f32x4 accg[4][2] = {}; f32x4 accu[4][2] = {};

    for (int kb = 0; kb < H_DIM; kb += 64) {
        __syncthreads();
        #pragma unroll
        for (int c = 0; c < 4; c++)
            gload16(srcA[c] + kb, (ushort*)As + (wvu * 4 + c) * 512);
        float4 g0 = *(const float4*)(wgrow + kb);
        float4 g1 = *(const float4*)(wgrow + kb + 4);
        *(uint4*)(&Bg[bo]) = pack8(g0, g1);
        float4 u0 = *(const float4*)(wurow + kb);
        float4 u1 = *(const float4*)(wurow + kb + 4);
        *(uint4*)(&Bu[bo]) = pack8(u0, u1);
        __syncthreads();

        #pragma unroll
        for (int kk = 0; kk < 2; kk++) {
            int kby = kk * 64 + lk * 16;
            short8 a[4];
            #pragma unroll
            for (int m = 0; m < 4; m++) {
                int row = wm * 64 + m * 16 + lr;
                a[m] = *(const short8*)(&As[(row * 128 + (kby ^ rsw)) >> 1]);
            }
            #pragma unroll
            for (int n = 0; n < 2; n++) {
                int rowb = wn * 32 + n * 16 + lr;
                int boff = (rowb * 128 + (kby ^ rsw)) >> 1;
                short8 bg8 = *(const short8*)(&Bg[boff]);
                short8 bu8 = *(const short8*)(&Bu[boff]);
                #pragma unroll
                for (int m = 0; m < 4; m++) {
                    accg[m][n] = __builtin_amdgcn_mfma_f32_16x16x32_bf16(a[m], bg8, accg[m][n], 0, 0, 0);
                    accu[m][n] = __builtin_amdgcn_mfma_f32_16x16x32_bf16(a[m], bu8, accu[m][n], 0, 0, 0);
                }
            }
        }
    }

    #pragma unroll
    for (int m = 0; m < 4; m++) {
        #pragma unroll
        for (int r = 0; r < 4; r++) {
            int lrow = wm * 64 + m * 16 + lk * 4 + r;
            if (row0 + lrow < ne) {
                size_t rb = (size_t)(base + row0 + lrow) * F_DIM + nb;
                #pragma unroll
                for (int n = 0; n < 2; n++) {
                    float g = accg[m][n][r], u = accu[m][n][r];
                    float hv = g / (1.f + __expf(-g)) * u;
                    hbuf[rb + wn * 32 + n * 16 + lr] = f2bf(hv);
                }
            }
        }
    }
}

// ---- grouped GEMM2: ybuf[p] = h[p] Wd^T  (R12-exact body) --------------
// BM=256 x BN=128 x BK=64, 512 thr = 8 waves (4m x 2n), wave tile 64x64.
__global__ __launch_bounds__(512, 2) void k_gemm2(
        const ushort* __restrict__ hbuf, const float* __restrict__ wd,
        const int* __restrict__ off, float* __restrict__ ybuf) {
    __shared__ __align__(16) ushort As[256 * 64];   // 32 KB
    __shared__ __align__(16) ushort Bs[128 * 64];   // 16 KB

    int e = blockIdx.y >> 3, mt = blockIdx.y & 7;
    int base = off[e], ne = off[e + 1] - base;
    int row0 = mt * 256;
    if (row0 >= ne) return;
    int nb = blockIdx.x * 128;

    int tid = threadIdx.x;
    int wv = tid >> 6, l = tid & 63;
    int lr = l & 15, lk = l >> 4;
    int wm = wv >> 1, wn = wv & 1;

    int wvu = __builtin_amdgcn_readfirstlane(wv);
    const ushort* srcA[4];
    int sslot = 8 * ((l & 7) ^ ((l >> 3) & 7));
    #pragma unroll
    for (int c = 0; c < 4; c++) {
        int r = (wvu * 4 + c) * 8 + (l >> 3);
        int pp = base + min(row0 + r, ne - 1);
        srcA[c] = hbuf + (size_t)pp * F_DIM + sslot;
    }

    int brow = tid >> 2, bs = tid & 3;
    const float* wdrow = wd + ((size_t)e * H_DIM + nb + brow) * F_DIM + bs * 16;
    int bsw = (brow & 7) << 4;
    int bo0 = brow * 64 + (((bs * 32) ^ bsw) >> 1);
    int bo1 = brow * 64 + (((bs * 32 + 16) ^ bsw) >> 1);

    int rsw = (lr & 7) << 4;

    f32x4 acc[4][4] = {};

    for (int kb = 0; kb < F_DIM; kb += 64) {
        __syncthreads();
        #pragma unroll
        for (int c = 0; c < 4; c++)
            gload16(srcA[c] + kb, (ushort*)As + (wvu * 4 + c) * 512);
        float4 b0 = *(const float4*)(wdrow + kb);
        float4 b1 = *(const float4*)(wdrow + kb + 4);
        float4 b2 = *(const float4*)(wdrow + kb + 8);
        float4 b3 = *(const float4*)(wdrow + kb + 12);
        *(uint4*)(&Bs[bo0]) = pack8(b0, b1);
        *(uint4*)(&Bs[bo1]) = pack8(b2, b3);
        __syncthreads();

        #pragma unroll
        for (int kk = 0; kk < 2; kk++) {
            int kby = kk * 64 + lk * 16;
            short8 a[4];
            #pragma unroll
            for (int m = 0; m < 4; m++) {
                int row = wm * 64 + m * 16 + lr;
                a[m] = *(const short8*)(&As[(row * 128 + (kby ^ rsw)) >> 1]);
            }
            #pragma unroll
            for (int n = 0; n < 4; n++) {
                int rowb = wn * 64 + n * 16 + lr;
                short8 b8 = *(const short8*)(&Bs[(rowb * 128 + (kby ^ rsw)) >> 1]);
                #pragma unroll
                for (int m = 0; m < 4; m++)
                    acc[m][n] = __builtin_amdgcn_mfma_f32_16x16x32_bf16(a[m], b8, acc[m][n], 0, 0, 0);
            }
        }
    }

    #pragma unroll
    for (int m = 0; m < 4; m++) {
        #pragma unroll
        for (int r = 0; r < 4; r++) {
            int lrow = wm * 64 + m * 16 + lk * 4 + r;
            if (row0 + lrow < ne) {
                float* yrow = ybuf + (size_t)(base + row0 + lrow) * H_DIM + nb;
                #pragma unroll
                for (int n = 0; n < 4; n++)
                    yrow[wn * 64 + n * 16 + lr] = acc[m][n][r];
            }
        }
    }
}

// ---- combine: out[t] = w0*y[p0] + w1*y[p1] -----------------------------
__global__ void k_combine(const float* __restrict__ ybuf,
                          const float2* __restrict__ ew,
                          const int2* __restrict__ inv,
                          float* __restrict__ out) {
    int t = blockIdx.x;
    float2 w = ew[t];
    int2 pp = inv[t];
    const float4* y0 = (const float4*)(ybuf + (size_t)pp.x * H_DIM);
    const float4* y1 = (const float4*)(ybuf + (size_t)pp.y * H_DIM);
    float4* o = (float4*)(out + (size_t)t * H_DIM);
    for (int j = threadIdx.x; j < H_DIM / 4; j += blockDim.x) {
        float4 a = y0[j], b = y1[j];
        float4 r;
        r.x = w.x * a.x + w.y * b.x;
        r.y = w.x * a.y + w.y * b.y;
        r.z = w.x * a.z + w.y * b.z;
        r.w = w.x * a.w + w.y * b.w;
        o[j] = r;
    }
}

extern "C" void kernel_launch(void* const* d_in, const int* in_sizes, int n_in,
                              void* d_out, int out_size, void* d_ws, size_t ws_size,
                              hipStream_t stream) {
    const float* x  = (const float*)d_in[0];
    const float* gw = (const float*)d_in[1];
    const float* wg = (const float*)d_in[2];
    const float* wu = (const float*)d_in[3];
    const float* wd = (const float*)d_in[4];
    float* out = (float*)d_out;

    char* ws = (char*)d_ws;
    size_t o = 0;
    ushort* xb   = (ushort*)(ws + o); o += (size_t)T_TOK * H_DIM * 2;   //  8 MB
    ushort* hbuf = (ushort*)(ws + o); o += (size_t)NPAIR * F_DIM * 2;   // 32 MB
    float*  ybuf = (float*) (ws + o); o += (size_t)NPAIR * H_DIM * 4;   // 32 MB
    int*    ptok = (int*)   (ws + o); o += NPAIR * 4;
    int2*   eidx = (int2*)  (ws + o); o += T_TOK * 8;
    float2* ew   = (float2*)(ws + o); o += T_TOK * 8;
    int2*   inv  = (int2*)  (ws + o); o += T_TOK * 8;
    int*    cnt  = (int*)   (ws + o); o += 256;
    int*    off  = (int*)   (ws + o); o += 256;

    hipMemsetAsync(cnt, 0, 256, stream);

    k_router <<<T_TOK / 4, 256, 0, stream>>>(x, gw, xb, eidx, ew, cnt);
    k_offfill<<<1, 256, 0, stream>>>(cnt, off, eidx, ptok, inv);

    dim3 g1(F_DIM / 64, E_NUM * 8);      // x: ntile(64), y: e*8 + mtile(256)
    k_gemm1<<<g1, 512, 0, stream>>>(xb, wg, wu, ptok, off, hbuf);
    dim3 g2(H_DIM / 128, E_NUM * 8);     // x: ntile(128), y: e*8 + mtile(256)
    k_gemm2<<<g2, 512, 0, stream>>>(hbuf, wd, off, ybuf);
    k_combine<<<T_TOK, 256, 0, stream>>>(ybuf, ew, inv, out);
}